// Round 5
// baseline (188.374 us; speedup 1.0000x reference)
//
#include <hip/hip_runtime.h>

#define Bsz 8
#define Ssz 4096
#define Dsz 128

typedef short bf16x8 __attribute__((ext_vector_type(8)));
typedef float f32x4 __attribute__((ext_vector_type(4)));
typedef int int2v __attribute__((ext_vector_type(2)));
typedef int int4v __attribute__((ext_vector_type(4)));
typedef unsigned int u32;

// pack two fp32 -> bf16x2 (round half-up: +0x8000 then take hi16 via v_perm)
__device__ __forceinline__ int pkbf(float a, float b) {
  u32 ra = __float_as_uint(a) + 0x8000u;
  u32 rb = __float_as_uint(b) + 0x8000u;
  return (int)__builtin_amdgcn_perm(rb, ra, 0x07060302u);  // [lo16=hi(a) | hi16=hi(b)]
}

// async global->LDS, 16B/lane: lds dest = wave-uniform base + lane*16
__device__ __forceinline__ void gll16(const void* g, void* l) {
  __builtin_amdgcn_global_load_lds((const __attribute__((address_space(1))) void*)g,
                                   (__attribute__((address_space(3))) void*)l, 16, 0, 0);
}

// Staged tile layouts (bf16), per 128-row tile, 16B granules:
//   Q/K: [ge=dchunk 0..15][s 0..127][8 d]   (granule = 8 consecutive d at fixed s)
//   V:   [gs=schunk 0..15][d 0..127][8 s]   (granule = 8 consecutive s at fixed d)
//   Wt:  [gd 0..15][e 0..127][8 d]          (W^T: 8 consecutive d at fixed e)

// ---------------- W transpose: fp32 W[3][d][e] -> bf16 Wt[3] staged, log2e folded into Wq ----
__global__ void wt_kernel(const float* __restrict__ w, short* __restrict__ Wt) {
  int g = blockIdx.x * 256 + threadIdx.x;  // 0..6143 granules
  int mat = g >> 11;
  int rem = g & 2047;
  int gd = rem >> 7;
  int e = rem & 127;
  float sc = (mat == 0) ? 1.44269504088896340736f : 1.0f;
  const float* src = w + mat * Dsz * Dsz + gd * 8 * Dsz + e;
  int pk[4];
  #pragma unroll
  for (int j = 0; j < 4; ++j)
    pk[j] = pkbf(src[(2 * j) * Dsz] * sc, src[(2 * j + 1) * Dsz] * sc);
  *(int4v*)&Wt[(size_t)g * 8] = *(const int4v*)pk;
}

// ---------------- Projection: X[BS,128] @ W -> Qs, Ks, Vs (staged bf16) ----------------
// grid 256: one 128-row X tile per block; X staged once, 3 matrices computed sequentially.
__global__ __launch_bounds__(256) void proj_kernel(
    const float* __restrict__ x, const short* __restrict__ Wt,
    short* __restrict__ Qs, short* __restrict__ Ks, short* __restrict__ Vs) {
  __shared__ short xb[128 * 136];  // X tile row-major, padded stride 272B (34.8KB)
  __shared__ short wb[16384];      // W^T staged [gd][e][8d] (32KB)
  __shared__ short ob[16384];      // output tile assembly (32KB)

  const int rb = blockIdx.x;
  const int t = threadIdx.x;
  const int lane = t & 63, wv = t >> 6;
  const int quad = lane >> 4, l15 = lane & 15;
  const int h0 = wv & 1, h1 = wv >> 1;

  // stage X: fp32 coalesced -> bf16 padded rows (b64 writes, conflict-free)
  {
    const float* xsrc = x + (size_t)rb * 128 * Dsz;
    #pragma unroll
    for (int p = 0; p < 16; ++p) {
      int idx4 = p * 256 + t;  // 4096 float4
      int row = idx4 >> 5, d0 = (idx4 & 31) << 2;
      f32x4 v = *(const f32x4*)&xsrc[idx4 * 4];
      int2v pr;
      pr[0] = pkbf(v[0], v[1]);
      pr[1] = pkbf(v[2], v[3]);
      *(int2v*)&xb[row * 136 + d0] = pr;
    }
  }

  for (int mat = 0; mat < 3; ++mat) {
    // stage Wt[mat] -> wb (linear async copy, 32 x 1KB)
    {
      const char* wsrc = (const char*)(Wt + (size_t)mat * 16384);
      #pragma unroll
      for (int i = 0; i < 8; ++i) {
        int p = wv * 8 + i;
        gll16(wsrc + p * 1024 + lane * 16, (char*)wb + p * 1024);
      }
    }
    __syncthreads();  // wb ready (vmcnt drained); xb ready (first mat)

    f32x4 acc[4][4];
    #pragma unroll
    for (int a = 0; a < 4; ++a)
      #pragma unroll
      for (int c = 0; c < 4; ++c) acc[a][c] = (f32x4){0.f, 0.f, 0.f, 0.f};

    if (mat < 2) {
      // C[e][s] = Wt(A, rows e) x X(B, cols s): lane holds 4 consecutive e at fixed s
      #pragma unroll
      for (int kc = 0; kc < 4; ++kc) {
        bf16x8 aw[4], bx[4];
        #pragma unroll
        for (int me = 0; me < 4; ++me)
          aw[me] = *(const bf16x8*)&wb[(kc * 4 + quad) * 1024 + (h0 * 64 + me * 16 + l15) * 8];
        #pragma unroll
        for (int ns = 0; ns < 4; ++ns)
          bx[ns] = *(const bf16x8*)&xb[(h1 * 64 + ns * 16 + l15) * 136 + kc * 32 + quad * 8];
        #pragma unroll
        for (int me = 0; me < 4; ++me)
          #pragma unroll
          for (int ns = 0; ns < 4; ++ns)
            acc[me][ns] = __builtin_amdgcn_mfma_f32_16x16x32_bf16(aw[me], bx[ns], acc[me][ns], 0, 0, 0);
      }
      __syncthreads();  // prev ob copy done before overwrite (no-op first mat)
      // epilogue: staged [ge][s][8e], b64 packed writes
      #pragma unroll
      for (int me = 0; me < 4; ++me)
        #pragma unroll
        for (int ns = 0; ns < 4; ++ns) {
          int e0 = h0 * 64 + me * 16 + quad * 4;
          int s = h1 * 64 + ns * 16 + l15;
          int2v pr;
          pr[0] = pkbf(acc[me][ns][0], acc[me][ns][1]);
          pr[1] = pkbf(acc[me][ns][2], acc[me][ns][3]);
          *(int2v*)&ob[(e0 >> 3) * 1024 + s * 8 + (e0 & 7)] = pr;
        }
    } else {
      // C[s][e] = X(A, rows s) x W(B, cols e): lane holds 4 consecutive s at fixed e
      #pragma unroll
      for (int kc = 0; kc < 4; ++kc) {
        bf16x8 ax[4], bw[4];
        #pragma unroll
        for (int ms = 0; ms < 4; ++ms)
          ax[ms] = *(const bf16x8*)&xb[(h0 * 64 + ms * 16 + l15) * 136 + kc * 32 + quad * 8];
        #pragma unroll
        for (int ne = 0; ne < 4; ++ne)
          bw[ne] = *(const bf16x8*)&wb[(kc * 4 + quad) * 1024 + (h1 * 64 + ne * 16 + l15) * 8];
        #pragma unroll
        for (int ms = 0; ms < 4; ++ms)
          #pragma unroll
          for (int ne = 0; ne < 4; ++ne)
            acc[ms][ne] = __builtin_amdgcn_mfma_f32_16x16x32_bf16(ax[ms], bw[ne], acc[ms][ne], 0, 0, 0);
      }
      __syncthreads();
      // epilogue: staged [gs][d][8s]
      #pragma unroll
      for (int ms = 0; ms < 4; ++ms)
        #pragma unroll
        for (int ne = 0; ne < 4; ++ne) {
          int s0 = h0 * 64 + ms * 16 + quad * 4;
          int e = h1 * 64 + ne * 16 + l15;
          int2v pr;
          pr[0] = pkbf(acc[ms][ne][0], acc[ms][ne][1]);
          pr[1] = pkbf(acc[ms][ne][2], acc[ms][ne][3]);
          *(int2v*)&ob[(s0 >> 3) * 1024 + e * 8 + (s0 & 7)] = pr;
        }
    }
    __syncthreads();  // ob complete
    short* dst = (mat == 0 ? Qs : (mat == 1 ? Ks : Vs)) + (size_t)rb * 16384;
    #pragma unroll
    for (int p = 0; p < 8; ++p) {
      int c = p * 256 + t;
      *(int4v*)&dst[c * 8] = *(const int4v*)&ob[c * 8];
    }
  }
}

// ---------------- Attention ----------------
// grid (8 b, 32 qt): q-tile 128, full 4096 keys per block (rowsum block-local).
// 4 waves. QK^T computed as S^T = K·Q^T (wave w owns k-slice w*16); PV: 2x2 (q-half x d-half).
// k-chunk 64/iter, 64 iters, double-buffered K/V staging via global_load_lds.
__global__ __launch_bounds__(256, 1) void attn_kernel(
    const short* __restrict__ Qs, const short* __restrict__ Ks,
    const short* __restrict__ Vs, float* __restrict__ acc_out) {
  __shared__ short kbuf[2][8192];   // 2 x 16KB: [ge 0..15][s' 0..63][8d]
  __shared__ short vbuf[2][8192];   // 2 x 16KB: [g' 0..7][d 0..127][8s]
  __shared__ short pbuf[128 * 72];  // P: [q][k], row stride 144B (18KB)
  __shared__ float rsbuf[128 * 4];
  __shared__ float linv[128];

  const int b = blockIdx.x;
  const int qt = blockIdx.y;
  const int t = threadIdx.x;
  const int w = t >> 6;
  const int lane = t & 63;
  const int quad = lane >> 4, l15 = lane & 15;
  const int qh = w >> 1, dh = w & 1;

  // Q fragments in registers: B-operand (lane n=q), 128 q x 128 d
  bf16x8 aq[8][4];
  {
    const short* qsrc = Qs + (size_t)(b * 32 + qt) * 16384;
    #pragma unroll
    for (int nq = 0; nq < 8; ++nq)
      #pragma unroll
      for (int kc = 0; kc < 4; ++kc)
        aq[nq][kc] = *(const bf16x8*)&qsrc[((kc * 4 + quad) * 128 + nq * 16 + l15) * 8];
  }

  f32x4 of[4][4];
  float rs[8];
  #pragma unroll
  for (int mq = 0; mq < 4; ++mq)
    #pragma unroll
    for (int nd = 0; nd < 4; ++nd) of[mq][nd] = (f32x4){0.f, 0.f, 0.f, 0.f};
  #pragma unroll
  for (int nq = 0; nq < 8; ++nq) rs[nq] = 0.f;

  const char* kbase = (const char*)(Ks + (size_t)b * 32 * 16384);
  const char* vbase = (const char*)(Vs + (size_t)b * 32 * 16384);

  // stage(it, buf): K chunk = 16 pieces [ge]*2048 + half*1024; V chunk = contiguous 16KB
  #define STAGE(it_, bf_)                                                              \
    {                                                                                  \
      int tile_ = (it_) >> 1, half_ = (it_) & 1;                                       \
      const char* ks_ = kbase + (size_t)tile_ * 32768;                                 \
      const char* vs_ = vbase + (size_t)tile_ * 32768 + half_ * 16384;                 \
      _Pragma("unroll")                                                                \
      for (int i_ = 0; i_ < 8; ++i_) {                                                 \
        int p_ = w * 8 + i_;                                                           \
        if (p_ < 16)                                                                   \
          gll16(ks_ + p_ * 2048 + half_ * 1024 + lane * 16, (char*)kbuf[bf_] + p_ * 1024); \
        else                                                                           \
          gll16(vs_ + (p_ - 16) * 1024 + lane * 16, (char*)vbuf[bf_] + (p_ - 16) * 1024);  \
      }                                                                                \
    }

  STAGE(0, 0);
  __syncthreads();

  for (int it = 0; it < 64; ++it) {
    const int cur = it & 1;
    if (it < 63) STAGE(it + 1, cur ^ 1);

    // ---- S^T = K·Q^T : wave w owns k-slice [w*16, w*16+16) of the 64-chunk ----
    f32x4 sc[8];
    #pragma unroll
    for (int nq = 0; nq < 8; ++nq) sc[nq] = (f32x4){0.f, 0.f, 0.f, 0.f};
    #pragma unroll
    for (int kc = 0; kc < 4; ++kc) {
      bf16x8 akf = *(const bf16x8*)&kbuf[cur][(kc * 4 + quad) * 512 + (w * 16 + l15) * 8];
      #pragma unroll
      for (int nq = 0; nq < 8; ++nq)
        sc[nq] = __builtin_amdgcn_mfma_f32_16x16x32_bf16(akf, aq[nq][kc], sc[nq], 0, 0, 0);
    }

    // ---- exp2, rowsum, packed b64 P writes (lane holds 4 consecutive k) ----
    const int k0 = w * 16 + quad * 4;
    #pragma unroll
    for (int nq = 0; nq < 8; ++nq) {
      float p0 = __builtin_amdgcn_exp2f(sc[nq][0]);
      float p1 = __builtin_amdgcn_exp2f(sc[nq][1]);
      float p2 = __builtin_amdgcn_exp2f(sc[nq][2]);
      float p3 = __builtin_amdgcn_exp2f(sc[nq][3]);
      rs[nq] += (p0 + p1) + (p2 + p3);
      int2v pr;
      pr[0] = pkbf(p0, p1);
      pr[1] = pkbf(p2, p3);
      *(int2v*)&pbuf[(nq * 16 + l15) * 72 + k0] = pr;
    }
    __syncthreads();  // P visible; prefetch drained (had full QK+exp to land)

    // ---- PV: O[128q x 128d] += P[128q x 64k] V[64k x 128d]; wave = (qh, dh) ----
    #pragma unroll
    for (int kc2 = 0; kc2 < 2; ++kc2) {
      bf16x8 pa[4], vf[4];
      #pragma unroll
      for (int mq = 0; mq < 4; ++mq)
        pa[mq] = *(const bf16x8*)&pbuf[(qh * 64 + mq * 16 + l15) * 72 + kc2 * 32 + quad * 8];
      #pragma unroll
      for (int nd = 0; nd < 4; ++nd)
        vf[nd] = *(const bf16x8*)&vbuf[cur][(kc2 * 4 + quad) * 1024 + (dh * 64 + nd * 16 + l15) * 8];
      #pragma unroll
      for (int mq = 0; mq < 4; ++mq)
        #pragma unroll
        for (int nd = 0; nd < 4; ++nd)
          of[mq][nd] = __builtin_amdgcn_mfma_f32_16x16x32_bf16(pa[mq], vf[nd], of[mq][nd], 0, 0, 0);
    }
    __syncthreads();  // pbuf / kbuf[cur] / vbuf[cur] free for reuse
  }

  // ---- rowsums: quad-reduce, combine 4 k-slices via LDS ----
  #pragma unroll
  for (int nq = 0; nq < 8; ++nq) {
    float v = rs[nq];
    v += __shfl_xor(v, 16, 64);
    v += __shfl_xor(v, 32, 64);
    rs[nq] = v;
  }
  if (lane < 16) {
    #pragma unroll
    for (int nq = 0; nq < 8; ++nq)
      rsbuf[(nq * 16 + l15) * 4 + w] = rs[nq];
  }
  __syncthreads();
  if (t < 128) {
    float l = rsbuf[t * 4] + rsbuf[t * 4 + 1] + rsbuf[t * 4 + 2] + rsbuf[t * 4 + 3];
    linv[t] = 1.f / (l * (float)Ssz);
  }
  __syncthreads();

  // ---- normalize, query-mean reduce, atomic accumulate ----
  float li[4][4];
  #pragma unroll
  for (int mq = 0; mq < 4; ++mq)
    #pragma unroll
    for (int r = 0; r < 4; ++r)
      li[mq][r] = linv[qh * 64 + mq * 16 + quad * 4 + r];

  #pragma unroll
  for (int nd = 0; nd < 4; ++nd) {
    float cs = 0.f;
    #pragma unroll
    for (int mq = 0; mq < 4; ++mq)
      #pragma unroll
      for (int r = 0; r < 4; ++r)
        cs += of[mq][nd][r] * li[mq][r];
    cs += __shfl_xor(cs, 16, 64);
    cs += __shfl_xor(cs, 32, 64);
    if (lane < 16)
      atomicAdd(&acc_out[b * Dsz + dh * 64 + nd * 16 + l15], cs);
  }
}

__global__ void finalize_kernel(const float* __restrict__ acc, float* __restrict__ out) {
  int i = blockIdx.x * 256 + threadIdx.x;
  if (i < Bsz * Dsz) out[i] = acc[i];
}

extern "C" void kernel_launch(void* const* d_in, const int* in_sizes, int n_in,
                              void* d_out, int out_size, void* d_ws, size_t ws_size,
                              hipStream_t stream) {
  const float* x = (const float*)d_in[0];  // fp32 [8,4096,128]
  const float* w = (const float*)d_in[1];  // fp32 [3,128,128]
  short* Qs = (short*)d_ws;                             // 8MB bf16 staged
  short* Ks = Qs + (size_t)Bsz * Ssz * Dsz;             // 8MB
  short* Vs = Ks + (size_t)Bsz * Ssz * Dsz;             // 8MB
  float* acc = (float*)(Vs + (size_t)Bsz * Ssz * Dsz);  // 4KB
  short* Wt = (short*)(acc + Bsz * Dsz);                // 96KB bf16 W^T staged

  wt_kernel<<<dim3(24), dim3(256), 0, stream>>>(w, Wt);
  hipMemsetAsync(acc, 0, Bsz * Dsz * sizeof(float), stream);
  proj_kernel<<<dim3(256), dim3(256), 0, stream>>>(x, Wt, Qs, Ks, Vs);
  attn_kernel<<<dim3(Bsz, Ssz / 128), dim3(256), 0, stream>>>(Qs, Ks, Vs, acc);
  finalize_kernel<<<dim3((Bsz * Dsz + 255) / 256), dim3(256), 0, stream>>>(acc, (float*)d_out);
}